// Round 3
// baseline (1345.939 us; speedup 1.0000x reference)
//
#include <hip/hip_runtime.h>
#include <stdint.h>
#include <math.h>

// Problem constants
#define D_MODEL 768
#define NTOK    4096      // B*S = 2*2048
#define SEQ     2048
#define NHEAD   12
#define HDIM    64
#define D_FF    3072
#define QKV_N   2304      // 3*D_MODEL

typedef unsigned short ushort_t;  // raw bf16 bits
typedef short  short8 __attribute__((ext_vector_type(8)));
typedef float  f32x4  __attribute__((ext_vector_type(4)));
typedef float  f32x16 __attribute__((ext_vector_type(16)));

__device__ __forceinline__ float b2f(ushort_t u) {
  union { unsigned int u; float f; } v; v.u = ((unsigned int)u) << 16; return v.f;
}
__device__ __forceinline__ ushort_t f2b(float f) {
  union { float f; unsigned int u; } v; v.f = f;
  unsigned int u = v.u;
  return (ushort_t)((u + 0x7fffu + ((u >> 16) & 1u)) >> 16);  // RNE
}
__device__ __forceinline__ unsigned cvtpk_bf16(float lo, float hi) {
  unsigned r;
  asm("v_cvt_pk_bf16_f32 %0, %1, %2" : "=v"(r) : "v"(lo), "v"(hi));
  return r;
}

// ---------------------------------------------------------------- layer transpose+cast
// All 4 weight matrices of one layer, [K,N] fp32 -> [N,K] bf16, one launch.
__global__ __launch_bounds__(256) void transpose_layer(
    const float* __restrict__ qkv_w, const float* __restrict__ out_w,
    const float* __restrict__ fc1_w, const float* __restrict__ fc2_w,
    ushort_t* __restrict__ qkvT, ushort_t* __restrict__ outT,
    ushort_t* __restrict__ f1T, ushort_t* __restrict__ f2T) {
  __shared__ ushort_t tile[32][33];
  int bid = blockIdx.x;
  const float* src; ushort_t* dst; int K, N, tn, tk;
  if (bid < 1728)      { src = qkv_w; dst = qkvT; K = 768;  N = 2304; tn = bid % 72;  tk = bid / 72; }
  else if (bid < 2304) { int b = bid - 1728; src = out_w; dst = outT; K = 768;  N = 768;  tn = b % 24; tk = b / 24; }
  else if (bid < 4608) { int b = bid - 2304; src = fc1_w; dst = f1T;  K = 768;  N = 3072; tn = b % 96; tk = b / 96; }
  else                 { int b = bid - 4608; src = fc2_w; dst = f2T;  K = 3072; N = 768;  tn = b % 24; tk = b / 24; }
  int n0 = tn * 32, k0 = tk * 32;
  int tx = threadIdx.x, ty = threadIdx.y;       // (32,8)
  #pragma unroll
  for (int i = 0; i < 32; i += 8)
    tile[ty + i][tx] = f2b(src[(size_t)(k0 + ty + i) * N + n0 + tx]);
  __syncthreads();
  #pragma unroll
  for (int i = 0; i < 32; i += 8)
    dst[(size_t)(n0 + ty + i) * K + k0 + tx] = tile[tx][ty + i];
}

// ---------------------------------------------------------------- layernorm
__global__ __launch_bounds__(256) void ln_kernel(const float* __restrict__ x,
                                                 const float* __restrict__ w,
                                                 const float* __restrict__ b,
                                                 ushort_t* __restrict__ out) {
  __shared__ float red[4];
  int tok = blockIdx.x, t = threadIdx.x;
  const float* xr = x + (size_t)tok * D_MODEL;
  float v0 = xr[t], v1 = xr[t + 256], v2 = xr[t + 512];
  float s = v0 + v1 + v2;
  #pragma unroll
  for (int o = 1; o < 64; o <<= 1) s += __shfl_xor(s, o, 64);
  if ((t & 63) == 0) red[t >> 6] = s;
  __syncthreads();
  float mean = (red[0] + red[1] + red[2] + red[3]) * (1.0f / 768.0f);
  __syncthreads();
  float d0 = v0 - mean, d1 = v1 - mean, d2 = v2 - mean;
  float q = d0 * d0 + d1 * d1 + d2 * d2;
  #pragma unroll
  for (int o = 1; o < 64; o <<= 1) q += __shfl_xor(q, o, 64);
  if ((t & 63) == 0) red[t >> 6] = q;
  __syncthreads();
  float var = (red[0] + red[1] + red[2] + red[3]) * (1.0f / 768.0f);
  float rs = rsqrtf(var + 1e-5f);
  ushort_t* orow = out + (size_t)tok * D_MODEL;
  orow[t]       = f2b(d0 * rs * w[t]       + b[t]);
  orow[t + 256] = f2b(d1 * rs * w[t + 256] + b[t + 256]);
  orow[t + 512] = f2b(d2 * rs * w[t + 512] + b[t + 512]);
}

// ---------------------------------------------------------------- GEMM (MFMA bf16)
// C[M,N] = A[M,K] * BT[N,K]^T + bias, 128 x TN tile, BK=32, 256 threads.
// DOUBLE-BUFFERED K-loop: one barrier/iter. XCD-chunked block swizzle (r11):
// consecutive work items (same A-panel row) colocate on one XCD's L2.
// EPI: 0 bias->bf16 | 1 bias+gelu->bf16 | 2 bias+resid->fp32
template <int EPI, int TN>
__global__ __launch_bounds__(256) void gemm_kernel(
    const ushort_t* __restrict__ A, const ushort_t* __restrict__ BT,
    const float* __restrict__ bias, const float* __restrict__ resid,
    float* __restrict__ Cf, ushort_t* __restrict__ Cb, int M, int N, int K) {
  constexpr int NI = (TN == 128) ? 4 : 2;
  __shared__ ushort_t As[2][128 * 32];
  __shared__ ushort_t Bs[2][TN * 32];
  int t = threadIdx.x;
  int lane = t & 63, wave = t >> 6;
  // XCD-aware bijective chunk swizzle (T1)
  int gx = gridDim.x;
  int nwg = gx * gridDim.y;
  int bid0 = blockIdx.y * gx + blockIdx.x;
  int qn = nwg >> 3, rm = nwg & 7;
  int xcd = bid0 & 7, pos = bid0 >> 3;
  int wg = (xcd < rm ? xcd * (qn + 1) : rm * (qn + 1) + (xcd - rm) * qn) + pos;
  int m0 = (wg / gx) * 128, n0 = (wg % gx) * TN;
  int wm = (TN == 128) ? (wave & 1) * 64 : wave * 32;
  int wn = (TN == 128) ? (wave >> 1) * 64 : 0;
  int quad = lane >> 4, l16 = lane & 15;
  int kq = quad * 8;
  int lrow = lane >> 2, lcol = (lane & 3) * 8;   // staging: 16B per lane

  auto stage = [&](int k0, int buf) {
    #pragma unroll
    for (int c = 0; c < 2; ++c) {
      int rowA = wave * 32 + c * 16 + lrow;
      const ushort_t* ga = A + (size_t)(m0 + rowA) * K + k0 + lcol;
      ushort_t* la = &As[buf][(wave * 32 + c * 16) * 32];
      __builtin_amdgcn_global_load_lds((const __attribute__((address_space(1))) void*)ga,
                                       (__attribute__((address_space(3))) void*)la, 16, 0, 0);
      if (TN == 128 || c == 0) {
        int rowB = (TN == 128) ? rowA : (wave * 16 + lrow);
        const ushort_t* gb = BT + (size_t)(n0 + rowB) * K + k0 + lcol;
        ushort_t* lb = (TN == 128) ? &Bs[buf][(wave * 32 + c * 16) * 32]
                                   : &Bs[buf][(wave * 16) * 32];
        __builtin_amdgcn_global_load_lds((const __attribute__((address_space(1))) void*)gb,
                                         (__attribute__((address_space(3))) void*)lb, 16, 0, 0);
      }
    }
  };

  f32x4 acc[NI][4];
  #pragma unroll
  for (int i = 0; i < NI; ++i)
    #pragma unroll
    for (int j = 0; j < 4; ++j) acc[i][j] = (f32x4){0.f, 0.f, 0.f, 0.f};

  stage(0, 0);                      // prologue prefetch
  int nk = K / 32;
  for (int ki = 0; ki < nk; ++ki) {
    int cur = ki & 1;
    __syncthreads();                // tile ki resident; prev reads of buf[cur^1] done
    if (ki + 1 < nk) stage((ki + 1) * 32, cur ^ 1);
    short8 af[NI], bf[4];
    #pragma unroll
    for (int i = 0; i < NI; ++i)
      af[i] = *(const short8*)&As[cur][(wm + i * 16 + l16) * 32 + kq];
    #pragma unroll
    for (int j = 0; j < 4; ++j)
      bf[j] = *(const short8*)&Bs[cur][(wn + j * 16 + l16) * 32 + kq];
    #pragma unroll
    for (int i = 0; i < NI; ++i)
      #pragma unroll
      for (int j = 0; j < 4; ++j)
        acc[i][j] = __builtin_amdgcn_mfma_f32_16x16x32_bf16(af[i], bf[j], acc[i][j], 0, 0, 0);
  }

  #pragma unroll
  for (int i = 0; i < NI; ++i) {
    #pragma unroll
    for (int j = 0; j < 4; ++j) {
      int col = n0 + wn + j * 16 + l16;
      float bv = bias[col];
      #pragma unroll
      for (int r = 0; r < 4; ++r) {
        int row = m0 + wm + i * 16 + quad * 4 + r;
        float v = acc[i][j][r] + bv;
        if (EPI == 1) v = 0.5f * v * (1.0f + erff(v * 0.70710678118654752f));
        if (EPI == 2) v += resid[(size_t)row * N + col];
        if (EPI == 2) Cf[(size_t)row * N + col] = v;
        else          Cb[(size_t)row * N + col] = f2b(v);
      }
    }
  }
}

// ---------------------------------------------------------------- attention (MFMA 32x32, key-split waves)
// qkv bf16 [NTOK, 2304]; token t, head hd: [hd*192 + (q:0|k:64|v:128) + d]
// r11: LDS-volume fix. r10's wave-pairs read IDENTICAL K/V fragments (A/B
// operands don't depend on the wave's q-block) -> half the LDS reads were
// redundant, and the LDS pipe was ~100% busy (3100 cyc/superstep measured).
// Now: superstep = 128 keys; wave w owns keys [32w, 32w+32) x ALL 64 q-rows
// (Q duplicated in registers: cheap). Per wave per superstep: 4 K-reads +
// 4 V-reads (was 16), same 16 MFMA, same 32 exp2. Partial O/lsum over
// disjoint key sets are additive (fixed-max softmax) -> tree-combine via LDS
// once at the end. XCD-chunked swizzle: all 32 q-blocks of one head land on
// one XCD -> 786KB K/V slice L2-resident.
#define KPAD 136   // Vt key-stride (128 + 8): 8-lane read groups hit distinct banks
__global__ __launch_bounds__(256, 3) void attn_kernel(const ushort_t* __restrict__ qkv,
                                                      ushort_t* __restrict__ out) {
  __shared__ __align__(16) ushort_t smem[128 * 72 + 64 * KPAD];   // Ks | Vt (35840 B)
  ushort_t* Ks = smem;                 // [key128][d64] pad 72
  ushort_t* Vt = smem + 128 * 72;      // [d64][key128] pad KPAD
  int t = threadIdx.x;
  int lane = t & 63, wave = t >> 6;
  int l31 = lane & 31, h = lane >> 5, h8 = h * 8;
  // XCD-aware swizzle: 3 heads per XCD -> K/V L2-resident
  int bid0 = blockIdx.y * 32 + blockIdx.x;       // grid (32, 24), nwg = 768
  int wg = (bid0 & 7) * 96 + (bid0 >> 3);
  int qt = wg & 31;
  int bh = wg >> 5;
  int b = bh / NHEAD, hd = bh % NHEAD;
  size_t base = (size_t)b * SEQ * QKV_N + hd * 192;
  int w32 = wave * 32;                 // wave's key window within superstep

  const float kscale = 0.125f * 1.44269504088896f;  // scale * log2(e)

  // Q fragments, BOTH q-halves: B-operand col = q = 32*qh + l31, elem e <-> d = 16*ks + 8*h + e
  short8 qf[2][4];
  #pragma unroll
  for (int qh = 0; qh < 2; ++qh) {
    const ushort_t* qp = qkv + base + (size_t)(qt * 64 + qh * 32 + l31) * QKV_N + h8;
    #pragma unroll
    for (int ks = 0; ks < 4; ++ks) qf[qh][ks] = *(const short8*)(qp + ks * 16);
  }

  // staging (256 threads stage the whole 128-key superstep):
  // K: thread -> row krow (0..127), 32 d-elems at kcol; 4x b128 LDS writes
  // V: thread -> key-pair (2kp, 2kp+1), 16 d at vdb; packed b32 transposed writes
  int krow = t >> 1, kcol = (t & 1) * 32;
  int kp = t & 63, vdb = (t >> 6) * 16;
  short8 kr[4], va[2], vb[2];
  auto kv_load = [&](int sbase) {
    const ushort_t* gk = qkv + base + (size_t)(sbase + krow) * QKV_N + 64 + kcol;
    #pragma unroll
    for (int i = 0; i < 4; ++i) kr[i] = *(const short8*)(gk + i * 8);
    const ushort_t* gv = qkv + base + (size_t)(sbase + 2 * kp) * QKV_N + 128 + vdb;
    va[0] = *(const short8*)gv;           va[1] = *(const short8*)(gv + 8);
    vb[0] = *(const short8*)(gv + QKV_N); vb[1] = *(const short8*)(gv + QKV_N + 8);
  };
  auto kv_write = [&]() {
    #pragma unroll
    for (int i = 0; i < 4; ++i)
      *(short8*)&Ks[krow * 72 + kcol + i * 8] = kr[i];
    unsigned* vtw = (unsigned*)&Vt[0];
    #pragma unroll
    for (int half = 0; half < 2; ++half)
      #pragma unroll
      for (int e = 0; e < 8; ++e) {
        unsigned pk = (unsigned)(unsigned short)va[half][e] |
                      ((unsigned)(unsigned short)vb[half][e] << 16);
        vtw[(vdb + half * 8 + e) * (KPAD / 2) + kp] = pk;
      }
    (void)0;
  };

  f32x16 o00, o01, o10, o11;     // [qh][dh]: q = 32qh + (8g+4h+r), d = 32dh + l31
  #pragma unroll
  for (int i = 0; i < 16; ++i) { o00[i] = 0.f; o01[i] = 0.f; o10[i] = 0.f; o11[i] = 0.f; }
  float ls0 = 0.f, ls1 = 0.f;    // partial denominators, q = l31 (own-h key rows)

  kv_load(0);
  for (int it = 0; it < SEQ / 128; ++it) {
    kv_write();
    __syncthreads();                       // staged; prev-iter reads already fenced below
    if (it + 1 < SEQ / 128) kv_load((it + 1) * 128);

    // ---- QK^T (swapped): S^T[key, q]; A = K (wave's 32 keys), B = Q halves
    f32x16 s0, s1;
    #pragma unroll
    for (int i = 0; i < 16; ++i) { s0[i] = 0.f; s1[i] = 0.f; }
    __builtin_amdgcn_s_setprio(1);
    #pragma unroll
    for (int ks = 0; ks < 4; ++ks) {
      short8 kf = *(const short8*)&Ks[(w32 + l31) * 72 + ks * 16 + h8];
      s0 = __builtin_amdgcn_mfma_f32_32x32x16_bf16(kf, qf[0][ks], s0, 0, 0, 0);
      s1 = __builtin_amdgcn_mfma_f32_32x32x16_bf16(kf, qf[1][ks], s1, 0, 0, 0);
    }
    __builtin_amdgcn_s_setprio(0);

    // ---- softmax numerator (fixed max = 0); acc reg (4g+r) <-> key = w32 + 8g + 4h + r
    unsigned wpk0[4][2], wpk1[4][2];
    #pragma unroll
    for (int g = 0; g < 4; ++g) {
      float p0 = exp2f(s0[4 * g + 0] * kscale), p1 = exp2f(s0[4 * g + 1] * kscale);
      float p2 = exp2f(s0[4 * g + 2] * kscale), p3 = exp2f(s0[4 * g + 3] * kscale);
      ls0 += (p0 + p1) + (p2 + p3);
      wpk0[g][0] = cvtpk_bf16(p0, p1);
      wpk0[g][1] = cvtpk_bf16(p2, p3);
    }
    #pragma unroll
    for (int g = 0; g < 4; ++g) {
      float p0 = exp2f(s1[4 * g + 0] * kscale), p1 = exp2f(s1[4 * g + 1] * kscale);
      float p2 = exp2f(s1[4 * g + 2] * kscale), p3 = exp2f(s1[4 * g + 3] * kscale);
      ls1 += (p0 + p1) + (p2 + p3);
      wpk1[g][0] = cvtpk_bf16(p0, p1);
      wpk1[g][1] = cvtpk_bf16(p2, p3);
    }

    // ---- PV: O[q, d] += P[q, keys] * V[keys, d]; A-frags in-register via shfl exchange
    #pragma unroll
    for (int k4 = 0; k4 < 2; ++k4) {
      int j2 = k4 * 2;
      unsigned f0[4], f1[4];
      #pragma unroll
      for (int c = 0; c < 2; ++c) {
        unsigned a0 = wpk0[j2][c], b0 = wpk0[j2 + 1][c];
        unsigned s0w = h ? a0 : b0;
        unsigned r0 = (unsigned)__shfl_xor((int)s0w, 32, 64);
        f0[c] = h ? r0 : a0;  f0[2 + c] = h ? b0 : r0;
        unsigned a1 = wpk1[j2][c], b1 = wpk1[j2 + 1][c];
        unsigned s1w = h ? a1 : b1;
        unsigned r1 = (unsigned)__shfl_xor((int)s1w, 32, 64);
        f1[c] = h ? r1 : a1;  f1[2 + c] = h ? b1 : r1;
      }
      union { unsigned u[4]; short8 s8; } u0, u1;
      u0.u[0] = f0[0]; u0.u[1] = f0[1]; u0.u[2] = f0[2]; u0.u[3] = f0[3];
      u1.u[0] = f1[0]; u1.u[1] = f1[1]; u1.u[2] = f1[2]; u1.u[3] = f1[3];
      short8 ap0 = u0.s8, ap1 = u1.s8;
      short8 v0 = *(const short8*)&Vt[(size_t)(l31)      * KPAD + w32 + k4 * 16 + h8];
      short8 v1 = *(const short8*)&Vt[(size_t)(32 + l31) * KPAD + w32 + k4 * 16 + h8];
      __builtin_amdgcn_s_setprio(1);
      o00 = __builtin_amdgcn_mfma_f32_32x32x16_bf16(ap0, v0, o00, 0, 0, 0);
      o01 = __builtin_amdgcn_mfma_f32_32x32x16_bf16(ap0, v1, o01, 0, 0, 0);
      o10 = __builtin_amdgcn_mfma_f32_32x32x16_bf16(ap1, v0, o10, 0, 0, 0);
      o11 = __builtin_amdgcn_mfma_f32_32x32x16_bf16(ap1, v1, o11, 0, 0, 0);
      __builtin_amdgcn_s_setprio(0);
    }
    __syncthreads();                       // all reads done before next superstep's writes
  }

  // fold h-partner (each lane's ls covers only its own-h 16 key-rows per superstep)
  ls0 += __shfl_xor(ls0, 32, 64);
  ls1 += __shfl_xor(ls1, 32, 64);

  // ---- cross-wave combine (partials over disjoint key sets; additive)
  float* slab = (float*)&smem[0];
  // phase 1: waves 2,3 dump full state; waves 0,1 absorb (stride 68 dwords: conflict-free)
  if (wave >= 2) {
    float* s = slab + (size_t)((wave - 2) * 64 + lane) * 68;
    #pragma unroll
    for (int i = 0; i < 16; ++i) {
      s[i] = o00[i]; s[16 + i] = o01[i]; s[32 + i] = o10[i]; s[48 + i] = o11[i];
    }
    s[64] = ls0; s[65] = ls1;
  }
  __syncthreads();
  if (wave < 2) {
    float* s = slab + (size_t)(wave * 64 + lane) * 68;
    #pragma unroll
    for (int i = 0; i < 16; ++i) {
      o00[i] += s[i]; o01[i] += s[16 + i]; o10[i] += s[32 + i]; o11[i] += s[48 + i];
    }
    ls0 += s[64]; ls1 += s[65];
  }
  __syncthreads();
  // phase 2: swap halves between waves 0,1 (wave0 -> full qh0, wave1 -> full qh1)
  if (wave == 1) {
    float* s = slab + (size_t)lane * 36;
    #pragma unroll
    for (int i = 0; i < 16; ++i) { s[i] = o00[i]; s[16 + i] = o01[i]; }
    s[32] = ls0;
  }
  if (wave == 0) {
    float* s = slab + (size_t)(64 + lane) * 36;
    #pragma unroll
    for (int i = 0; i < 16; ++i) { s[i] = o10[i]; s[16 + i] = o11[i]; }
    s[32] = ls1;
  }
  __syncthreads();
  if (wave < 2) {
    float* s = slab + (size_t)(wave == 0 ? lane : 64 + lane) * 36;
    f32x16 pa, pb; float lsf;
    if (wave == 0) {
      #pragma unroll
      for (int i = 0; i < 16; ++i) { pa[i] = o00[i] + s[i]; pb[i] = o01[i] + s[16 + i]; }
      lsf = ls0 + s[32];
    } else {
      #pragma unroll
      for (int i = 0; i < 16; ++i) { pa[i] = o10[i] + s[i]; pb[i] = o11[i] + s[16 + i]; }
      lsf = ls1 + s[32];
    }
    // epilogue: rows q = qt*64 + 32*wave + (8g+4h+r); cols d = l31 / 32+l31
    size_t ob = (size_t)(b * SEQ + qt * 64 + wave * 32) * D_MODEL + hd * HDIM;
    #pragma unroll
    for (int g = 0; g < 4; ++g) {
      #pragma unroll
      for (int r = 0; r < 4; ++r) {
        int reg = 4 * g + r;
        int qrow = 8 * g + 4 * h + r;
        float inv = 1.0f / __shfl(lsf, qrow, 64);
        ushort_t* orow = out + ob + (size_t)qrow * D_MODEL;
        orow[l31]      = f2b(pa[reg] * inv);
        orow[32 + l31] = f2b(pb[reg] * inv);
      }
    }
  }
}

// ---------------------------------------------------------------- launch
extern "C" void kernel_launch(void* const* d_in, const int* in_sizes, int n_in,
                              void* d_out, int out_size, void* d_ws, size_t ws_size,
                              hipStream_t stream) {
  const float* x_in  = (const float*)d_in[0];
  const float* qkv_w = (const float*)d_in[1];
  const float* qkv_b = (const float*)d_in[2];
  const float* out_w = (const float*)d_in[3];
  const float* out_b = (const float*)d_in[4];
  const float* ln1_w = (const float*)d_in[5];
  const float* ln1_b = (const float*)d_in[6];
  const float* fc1_w = (const float*)d_in[7];
  const float* fc1_b = (const float*)d_in[8];
  const float* fc2_w = (const float*)d_in[9];
  const float* fc2_b = (const float*)d_in[10];
  const float* ln2_w = (const float*)d_in[11];
  const float* ln2_b = (const float*)d_in[12];

  char* ws = (char*)d_ws;
  size_t off = 0;
  auto alloc = [&](size_t bytes) -> void* {
    void* p = ws + off; off += (bytes + 255) & ~(size_t)255; return p;
  };
  float*    buf_x  = (float*)   alloc((size_t)NTOK * D_MODEL * 4);
  float*    buf_x2 = (float*)   alloc((size_t)NTOK * D_MODEL * 4);
  ushort_t* bigb   = (ushort_t*)alloc((size_t)NTOK * D_FF * 2);     // qkv_a / mlp_b union
  ushort_t* h_b    = (ushort_t*)alloc((size_t)NTOK * D_MODEL * 2);
  ushort_t* at_b   = (ushort_t*)alloc((size_t)NTOK * D_MODEL * 2);
  ushort_t* qkvT   = (ushort_t*)alloc((size_t)QKV_N * D_MODEL * 2);
  ushort_t* outT   = (ushort_t*)alloc((size_t)D_MODEL * D_MODEL * 2);
  ushort_t* f1T    = (ushort_t*)alloc((size_t)D_FF * D_MODEL * 2);
  ushort_t* f2T    = (ushort_t*)alloc((size_t)D_MODEL * D_FF * 2);

  ushort_t* qkv_a = bigb;
  ushort_t* mlp_b = bigb;

  for (int l = 0; l < 4; ++l) {
    const float* resid_in = (l == 0) ? x_in : buf_x;
    transpose_layer<<<6912, dim3(32, 8), 0, stream>>>(
        qkv_w + (size_t)l * D_MODEL * QKV_N, out_w + (size_t)l * D_MODEL * D_MODEL,
        fc1_w + (size_t)l * D_MODEL * D_FF,  fc2_w + (size_t)l * D_FF * D_MODEL,
        qkvT, outT, f1T, f2T);
    ln_kernel<<<NTOK, 256, 0, stream>>>(resid_in, ln1_w + l * D_MODEL, ln1_b + l * D_MODEL, h_b);
    gemm_kernel<0, 128><<<dim3(QKV_N / 128, NTOK / 128), 256, 0, stream>>>(
        h_b, qkvT, qkv_b + l * QKV_N, nullptr, nullptr, qkv_a, NTOK, QKV_N, D_MODEL);
    attn_kernel<<<dim3(SEQ / 64, 2 * NHEAD), 256, 0, stream>>>(qkv_a, at_b);
    gemm_kernel<2, 64><<<dim3(D_MODEL / 64, NTOK / 128), 256, 0, stream>>>(
        at_b, outT, out_b + l * D_MODEL, resid_in, buf_x2, nullptr, NTOK, D_MODEL, D_MODEL);
    ln_kernel<<<NTOK, 256, 0, stream>>>(buf_x2, ln2_w + l * D_MODEL, ln2_b + l * D_MODEL, h_b);
    gemm_kernel<1, 128><<<dim3(D_FF / 128, NTOK / 128), 256, 0, stream>>>(
        h_b, f1T, fc1_b + l * D_FF, nullptr, nullptr, mlp_b, NTOK, D_FF, D_MODEL);
    float* x_next = (l < 3) ? buf_x : (float*)d_out;
    gemm_kernel<2, 64><<<dim3(D_MODEL / 64, NTOK / 128), 256, 0, stream>>>(
        mlp_b, f2T, fc2_b + l * D_MODEL, buf_x2, x_next, nullptr, NTOK, D_MODEL, D_FF);
  }
  (void)in_sizes; (void)n_in; (void)out_size; (void)ws_size;
}

// Round 4
// 960.326 us; speedup vs baseline: 1.4015x; 1.4015x over previous
//
#include <hip/hip_runtime.h>
#include <stdint.h>
#include <math.h>

// Problem constants
#define D_MODEL 768
#define NTOK    4096      // B*S = 2*2048
#define SEQ     2048
#define NHEAD   12
#define HDIM    64
#define D_FF    3072
#define QKV_N   2304      // 3*D_MODEL

typedef unsigned short ushort_t;  // raw bf16 bits
typedef short  short8 __attribute__((ext_vector_type(8)));
typedef float  f32x4  __attribute__((ext_vector_type(4)));
typedef float  f32x16 __attribute__((ext_vector_type(16)));

__device__ __forceinline__ float b2f(ushort_t u) {
  union { unsigned int u; float f; } v; v.u = ((unsigned int)u) << 16; return v.f;
}
__device__ __forceinline__ ushort_t f2b(float f) {
  union { float f; unsigned int u; } v; v.f = f;
  unsigned int u = v.u;
  return (ushort_t)((u + 0x7fffu + ((u >> 16) & 1u)) >> 16);  // RNE
}
__device__ __forceinline__ unsigned cvtpk_bf16(float lo, float hi) {
  unsigned r;
  asm("v_cvt_pk_bf16_f32 %0, %1, %2" : "=v"(r) : "v"(lo), "v"(hi));
  return r;
}

// ---------------------------------------------------------------- layer transpose+cast
// All 4 weight matrices of one layer, [K,N] fp32 -> [N,K] bf16, one launch.
__global__ __launch_bounds__(256) void transpose_layer(
    const float* __restrict__ qkv_w, const float* __restrict__ out_w,
    const float* __restrict__ fc1_w, const float* __restrict__ fc2_w,
    ushort_t* __restrict__ qkvT, ushort_t* __restrict__ outT,
    ushort_t* __restrict__ f1T, ushort_t* __restrict__ f2T) {
  __shared__ ushort_t tile[32][33];
  int bid = blockIdx.x;
  const float* src; ushort_t* dst; int K, N, tn, tk;
  if (bid < 1728)      { src = qkv_w; dst = qkvT; K = 768;  N = 2304; tn = bid % 72;  tk = bid / 72; }
  else if (bid < 2304) { int b = bid - 1728; src = out_w; dst = outT; K = 768;  N = 768;  tn = b % 24; tk = b / 24; }
  else if (bid < 4608) { int b = bid - 2304; src = fc1_w; dst = f1T;  K = 768;  N = 3072; tn = b % 96; tk = b / 96; }
  else                 { int b = bid - 4608; src = fc2_w; dst = f2T;  K = 3072; N = 768;  tn = b % 24; tk = b / 24; }
  int n0 = tn * 32, k0 = tk * 32;
  int tx = threadIdx.x, ty = threadIdx.y;       // (32,8)
  #pragma unroll
  for (int i = 0; i < 32; i += 8)
    tile[ty + i][tx] = f2b(src[(size_t)(k0 + ty + i) * N + n0 + tx]);
  __syncthreads();
  #pragma unroll
  for (int i = 0; i < 32; i += 8)
    dst[(size_t)(n0 + ty + i) * K + k0 + tx] = tile[tx][ty + i];
}

// ---------------------------------------------------------------- layernorm
__global__ __launch_bounds__(256) void ln_kernel(const float* __restrict__ x,
                                                 const float* __restrict__ w,
                                                 const float* __restrict__ b,
                                                 ushort_t* __restrict__ out) {
  __shared__ float red[4];
  int tok = blockIdx.x, t = threadIdx.x;
  const float* xr = x + (size_t)tok * D_MODEL;
  float v0 = xr[t], v1 = xr[t + 256], v2 = xr[t + 512];
  float s = v0 + v1 + v2;
  #pragma unroll
  for (int o = 1; o < 64; o <<= 1) s += __shfl_xor(s, o, 64);
  if ((t & 63) == 0) red[t >> 6] = s;
  __syncthreads();
  float mean = (red[0] + red[1] + red[2] + red[3]) * (1.0f / 768.0f);
  __syncthreads();
  float d0 = v0 - mean, d1 = v1 - mean, d2 = v2 - mean;
  float q = d0 * d0 + d1 * d1 + d2 * d2;
  #pragma unroll
  for (int o = 1; o < 64; o <<= 1) q += __shfl_xor(q, o, 64);
  if ((t & 63) == 0) red[t >> 6] = q;
  __syncthreads();
  float var = (red[0] + red[1] + red[2] + red[3]) * (1.0f / 768.0f);
  float rs = rsqrtf(var + 1e-5f);
  ushort_t* orow = out + (size_t)tok * D_MODEL;
  orow[t]       = f2b(d0 * rs * w[t]       + b[t]);
  orow[t + 256] = f2b(d1 * rs * w[t + 256] + b[t + 256]);
  orow[t + 512] = f2b(d2 * rs * w[t + 512] + b[t + 512]);
}

// ---------------------------------------------------------------- GEMM (MFMA bf16)
// C[M,N] = A[M,K] * BT[N,K]^T + bias, 128 x TN tile, BK=32, 256 threads.
// DOUBLE-BUFFERED K-loop: one barrier/iter. XCD-chunked block swizzle (kept
// from r3: non-attn time improved 738 -> 670us with it).
// EPI: 0 bias->bf16 | 1 bias+gelu->bf16 | 2 bias+resid->fp32
template <int EPI, int TN>
__global__ __launch_bounds__(256) void gemm_kernel(
    const ushort_t* __restrict__ A, const ushort_t* __restrict__ BT,
    const float* __restrict__ bias, const float* __restrict__ resid,
    float* __restrict__ Cf, ushort_t* __restrict__ Cb, int M, int N, int K) {
  constexpr int NI = (TN == 128) ? 4 : 2;
  __shared__ ushort_t As[2][128 * 32];
  __shared__ ushort_t Bs[2][TN * 32];
  int t = threadIdx.x;
  int lane = t & 63, wave = t >> 6;
  // XCD-aware bijective chunk swizzle (T1)
  int gx = gridDim.x;
  int nwg = gx * gridDim.y;
  int bid0 = blockIdx.y * gx + blockIdx.x;
  int qn = nwg >> 3, rm = nwg & 7;
  int xcd = bid0 & 7, pos = bid0 >> 3;
  int wg = (xcd < rm ? xcd * (qn + 1) : rm * (qn + 1) + (xcd - rm) * qn) + pos;
  int m0 = (wg / gx) * 128, n0 = (wg % gx) * TN;
  int wm = (TN == 128) ? (wave & 1) * 64 : wave * 32;
  int wn = (TN == 128) ? (wave >> 1) * 64 : 0;
  int quad = lane >> 4, l16 = lane & 15;
  int kq = quad * 8;
  int lrow = lane >> 2, lcol = (lane & 3) * 8;   // staging: 16B per lane

  auto stage = [&](int k0, int buf) {
    #pragma unroll
    for (int c = 0; c < 2; ++c) {
      int rowA = wave * 32 + c * 16 + lrow;
      const ushort_t* ga = A + (size_t)(m0 + rowA) * K + k0 + lcol;
      ushort_t* la = &As[buf][(wave * 32 + c * 16) * 32];
      __builtin_amdgcn_global_load_lds((const __attribute__((address_space(1))) void*)ga,
                                       (__attribute__((address_space(3))) void*)la, 16, 0, 0);
      if (TN == 128 || c == 0) {
        int rowB = (TN == 128) ? rowA : (wave * 16 + lrow);
        const ushort_t* gb = BT + (size_t)(n0 + rowB) * K + k0 + lcol;
        ushort_t* lb = (TN == 128) ? &Bs[buf][(wave * 32 + c * 16) * 32]
                                   : &Bs[buf][(wave * 16) * 32];
        __builtin_amdgcn_global_load_lds((const __attribute__((address_space(1))) void*)gb,
                                         (__attribute__((address_space(3))) void*)lb, 16, 0, 0);
      }
    }
  };

  f32x4 acc[NI][4];
  #pragma unroll
  for (int i = 0; i < NI; ++i)
    #pragma unroll
    for (int j = 0; j < 4; ++j) acc[i][j] = (f32x4){0.f, 0.f, 0.f, 0.f};

  stage(0, 0);                      // prologue prefetch
  int nk = K / 32;
  for (int ki = 0; ki < nk; ++ki) {
    int cur = ki & 1;
    __syncthreads();                // tile ki resident; prev reads of buf[cur^1] done
    if (ki + 1 < nk) stage((ki + 1) * 32, cur ^ 1);
    short8 af[NI], bf[4];
    #pragma unroll
    for (int i = 0; i < NI; ++i)
      af[i] = *(const short8*)&As[cur][(wm + i * 16 + l16) * 32 + kq];
    #pragma unroll
    for (int j = 0; j < 4; ++j)
      bf[j] = *(const short8*)&Bs[cur][(wn + j * 16 + l16) * 32 + kq];
    #pragma unroll
    for (int i = 0; i < NI; ++i)
      #pragma unroll
      for (int j = 0; j < 4; ++j)
        acc[i][j] = __builtin_amdgcn_mfma_f32_16x16x32_bf16(af[i], bf[j], acc[i][j], 0, 0, 0);
  }

  #pragma unroll
  for (int i = 0; i < NI; ++i) {
    #pragma unroll
    for (int j = 0; j < 4; ++j) {
      int col = n0 + wn + j * 16 + l16;
      float bv = bias[col];
      #pragma unroll
      for (int r = 0; r < 4; ++r) {
        int row = m0 + wm + i * 16 + quad * 4 + r;
        float v = acc[i][j][r] + bv;
        if (EPI == 1) v = 0.5f * v * (1.0f + erff(v * 0.70710678118654752f));
        if (EPI == 2) v += resid[(size_t)row * N + col];
        if (EPI == 2) Cf[(size_t)row * N + col] = v;
        else          Cb[(size_t)row * N + col] = f2b(v);
      }
    }
  }
}

// ---------------------------------------------------------------- attention (MFMA 32x32, 2x2 wave partition)
// qkv bf16 [NTOK, 2304]; token t, head hd: [hd*192 + (q:0|k:64|v:128) + d]
// r12: fix r3's spill (WRITE_SIZE 6->92MB = scratch) by halving per-wave state.
// Back to r2's proven skeleton (q-tile 64, 256 thr, 3 blocks/CU, 36.8KB LDS,
// 128-key supersteps staged as 2 chunks), but waves partition (key-half x
// q-half): wave (kh=w&1, qh=w>>1) processes keys [32kh,+32) of BOTH chunks
// x q [32qh,+32). Per wave per 128 keys: 8 QK + 8 PV LDS reads (r2: 32).
// State: O 32 + S 16 + qf 16 + staging 32 regs -> ~120 VGPR, no spill.
// K-partials additive (fixed-max softmax) -> one LDS exchange at end.
// NO XCD swizzle here (r3: it cost ~100MB extra L2 misses).
__global__ __launch_bounds__(256, 3) void attn_kernel(const ushort_t* __restrict__ qkv,
                                                      ushort_t* __restrict__ out) {
  __shared__ __align__(16) ushort_t Ks[2][64 * 72];   // [chunk][key][d], pad 72
  __shared__ __align__(16) ushort_t Vt[2][64 * 72];   // [chunk][d][key], pad 72
  int t = threadIdx.x;
  int lane = t & 63, wave = t >> 6;
  int l31 = lane & 31, h = lane >> 5, h8 = h * 8;
  int kh = wave & 1, qh = wave >> 1;
  int kw = kh * 32;                    // wave's key window within each 64-key chunk
  int qt = blockIdx.x;
  int bh = blockIdx.y;
  int b = bh / NHEAD, hd = bh % NHEAD;
  size_t base = (size_t)b * SEQ * QKV_N + hd * 192;

  const float kscale = 0.125f * 1.44269504088896f;  // scale * log2(e)

  // Q fragments (own q-half): B-operand col = q = qh*32 + l31, elem e <-> d = 16*ks + 8*h + e
  short8 qf[4];
  {
    const ushort_t* qp = qkv + base + (size_t)(qt * 64 + qh * 32 + l31) * QKV_N + h8;
    #pragma unroll
    for (int ks = 0; ks < 4; ++ks) qf[ks] = *(const short8*)(qp + ks * 16);
  }

  // staging (256 threads stage the whole 128-key superstep into 2 chunks):
  // K: thread -> row krow (0..127), 32 d at kcol; 4x b128 writes
  // V: thread -> key-pair (2kp, 2kp+1), 16 d at vdb; packed b32 transposed writes
  int krow = t >> 1, kcol = (t & 1) * 32;
  int kcb = krow >> 6, krl = krow & 63;
  int kp = t & 63, vdb = (t >> 6) * 16;
  int vcb = kp >> 5, kpl = kp & 31;
  short8 kr[4], va[2], vb[2];
  auto kv_load = [&](int sbase) {
    const ushort_t* gk = qkv + base + (size_t)(sbase + krow) * QKV_N + 64 + kcol;
    #pragma unroll
    for (int i = 0; i < 4; ++i) kr[i] = *(const short8*)(gk + i * 8);
    const ushort_t* gv = qkv + base + (size_t)(sbase + 2 * kp) * QKV_N + 128 + vdb;
    va[0] = *(const short8*)gv;           va[1] = *(const short8*)(gv + 8);
    vb[0] = *(const short8*)(gv + QKV_N); vb[1] = *(const short8*)(gv + QKV_N + 8);
  };
  auto kv_write = [&]() {
    #pragma unroll
    for (int i = 0; i < 4; ++i)
      *(short8*)&Ks[kcb][krl * 72 + kcol + i * 8] = kr[i];
    unsigned* vtw = (unsigned*)&Vt[vcb][0];
    #pragma unroll
    for (int half = 0; half < 2; ++half)
      #pragma unroll
      for (int e = 0; e < 8; ++e) {
        unsigned pk = (unsigned)(unsigned short)va[half][e] |
                      ((unsigned)(unsigned short)vb[half][e] << 16);
        vtw[(vdb + half * 8 + e) * 36 + kpl] = pk;   // Vt[d][keys 2kpl, 2kpl+1]
      }
  };

  f32x16 o0, o1;                 // O[q = qh*32 + (8g+4h+r)][d = l31 / 32+l31]
  #pragma unroll
  for (int i = 0; i < 16; ++i) { o0[i] = 0.f; o1[i] = 0.f; }
  float ls = 0.f;                // partial denominator for q = qh*32 + l31

  kv_load(0);
  for (int it = 0; it < SEQ / 128; ++it) {
    kv_write();
    __syncthreads();                       // superstep staged; prev reads done
    if (it + 1 < SEQ / 128) kv_load((it + 1) * 128);

    #pragma unroll
    for (int c = 0; c < 2; ++c) {          // the two 64-key chunks
      // ---- QK^T (swapped): S^T[key, q]; A = K (own 32-key window), B = Q (own q-half)
      f32x16 s;
      #pragma unroll
      for (int i = 0; i < 16; ++i) s[i] = 0.f;
      __builtin_amdgcn_s_setprio(1);
      #pragma unroll
      for (int ks = 0; ks < 4; ++ks) {
        short8 kf = *(const short8*)&Ks[c][(kw + l31) * 72 + ks * 16 + h8];
        s = __builtin_amdgcn_mfma_f32_32x32x16_bf16(kf, qf[ks], s, 0, 0, 0);
      }
      __builtin_amdgcn_s_setprio(0);

      // ---- softmax numerator (fixed max = 0); reg (4g+r) <-> window-key = 8g+4h+r
      unsigned wpk[4][2];
      #pragma unroll
      for (int g = 0; g < 4; ++g) {
        float p0 = exp2f(s[4 * g + 0] * kscale), p1 = exp2f(s[4 * g + 1] * kscale);
        float p2 = exp2f(s[4 * g + 2] * kscale), p3 = exp2f(s[4 * g + 3] * kscale);
        ls += (p0 + p1) + (p2 + p3);
        wpk[g][0] = cvtpk_bf16(p0, p1);
        wpk[g][1] = cvtpk_bf16(p2, p3);
      }

      // ---- PV: O += P * V over own 32-key window; A-frag via half-wave exchange
      #pragma unroll
      for (int k4 = 0; k4 < 2; ++k4) {
        int j2 = k4 * 2;
        unsigned f[4];
        #pragma unroll
        for (int c2 = 0; c2 < 2; ++c2) {
          unsigned a  = wpk[j2][c2];        // window-keys 16k4 + 4h + {2c2, 2c2+1}
          unsigned b2 = wpk[j2 + 1][c2];    // window-keys 16k4 + 8 + 4h + {2c2, 2c2+1}
          unsigned snd = h ? a : b2;
          unsigned rcv = (unsigned)__shfl_xor((int)snd, 32, 64);
          f[c2]     = h ? rcv : a;
          f[2 + c2] = h ? b2 : rcv;
        }
        union { unsigned u[4]; short8 s8; } uc;
        uc.u[0] = f[0]; uc.u[1] = f[1]; uc.u[2] = f[2]; uc.u[3] = f[3];
        short8 ap = uc.s8;
        short8 v0 = *(const short8*)&Vt[c][(l31)      * 72 + kw + k4 * 16 + h8];
        short8 v1 = *(const short8*)&Vt[c][(32 + l31) * 72 + kw + k4 * 16 + h8];
        __builtin_amdgcn_s_setprio(1);
        o0 = __builtin_amdgcn_mfma_f32_32x32x16_bf16(ap, v0, o0, 0, 0, 0);
        o1 = __builtin_amdgcn_mfma_f32_32x32x16_bf16(ap, v1, o1, 0, 0, 0);
        __builtin_amdgcn_s_setprio(0);
      }
    }
    __syncthreads();                       // all reads done before next superstep writes
  }

  // ---- combine key-halves: wave (1,qh) -> wave (0,qh); partials additive
  float* slab = (float*)&Ks[0][0];         // 128 lanes x 33 f = 16896B (fits in Ks)
  if (kh == 1) {
    float* s = slab + (size_t)(qh * 64 + lane) * 33;
    #pragma unroll
    for (int i = 0; i < 16; ++i) { s[i] = o0[i]; s[16 + i] = o1[i]; }
    s[32] = ls;
  }
  __syncthreads();
  if (kh == 0) {
    float* s = slab + (size_t)(qh * 64 + lane) * 33;
    #pragma unroll
    for (int i = 0; i < 16; ++i) { o0[i] += s[i]; o1[i] += s[16 + i]; }
    ls += s[32];
    // fold h-partner (each lane's ls covers only own-h window rows)
    ls += __shfl_xor(ls, 32, 64);

    // epilogue: rows q = qt*64 + qh*32 + (8g+4h+r); cols d = l31 / 32+l31
    size_t ob = (size_t)(b * SEQ + qt * 64 + qh * 32) * D_MODEL + hd * HDIM;
    #pragma unroll
    for (int g = 0; g < 4; ++g) {
      #pragma unroll
      for (int r = 0; r < 4; ++r) {
        int reg = 4 * g + r;
        int qrow = 8 * g + 4 * h + r;
        float inv = 1.0f / __shfl(ls, qrow, 64);
        ushort_t* orow = out + ob + (size_t)qrow * D_MODEL;
        orow[l31]      = f2b(o0[reg] * inv);
        orow[32 + l31] = f2b(o1[reg] * inv);
      }
    }
  }
}

// ---------------------------------------------------------------- launch
extern "C" void kernel_launch(void* const* d_in, const int* in_sizes, int n_in,
                              void* d_out, int out_size, void* d_ws, size_t ws_size,
                              hipStream_t stream) {
  const float* x_in  = (const float*)d_in[0];
  const float* qkv_w = (const float*)d_in[1];
  const float* qkv_b = (const float*)d_in[2];
  const float* out_w = (const float*)d_in[3];
  const float* out_b = (const float*)d_in[4];
  const float* ln1_w = (const float*)d_in[5];
  const float* ln1_b = (const float*)d_in[6];
  const float* fc1_w = (const float*)d_in[7];
  const float* fc1_b = (const float*)d_in[8];
  const float* fc2_w = (const float*)d_in[9];
  const float* fc2_b = (const float*)d_in[10];
  const float* ln2_w = (const float*)d_in[11];
  const float* ln2_b = (const float*)d_in[12];

  char* ws = (char*)d_ws;
  size_t off = 0;
  auto alloc = [&](size_t bytes) -> void* {
    void* p = ws + off; off += (bytes + 255) & ~(size_t)255; return p;
  };
  float*    buf_x  = (float*)   alloc((size_t)NTOK * D_MODEL * 4);
  float*    buf_x2 = (float*)   alloc((size_t)NTOK * D_MODEL * 4);
  ushort_t* bigb   = (ushort_t*)alloc((size_t)NTOK * D_FF * 2);     // qkv_a / mlp_b union
  ushort_t* h_b    = (ushort_t*)alloc((size_t)NTOK * D_MODEL * 2);
  ushort_t* at_b   = (ushort_t*)alloc((size_t)NTOK * D_MODEL * 2);
  ushort_t* qkvT   = (ushort_t*)alloc((size_t)QKV_N * D_MODEL * 2);
  ushort_t* outT   = (ushort_t*)alloc((size_t)D_MODEL * D_MODEL * 2);
  ushort_t* f1T    = (ushort_t*)alloc((size_t)D_FF * D_MODEL * 2);
  ushort_t* f2T    = (ushort_t*)alloc((size_t)D_MODEL * D_FF * 2);

  ushort_t* qkv_a = bigb;
  ushort_t* mlp_b = bigb;

  for (int l = 0; l < 4; ++l) {
    const float* resid_in = (l == 0) ? x_in : buf_x;
    transpose_layer<<<6912, dim3(32, 8), 0, stream>>>(
        qkv_w + (size_t)l * D_MODEL * QKV_N, out_w + (size_t)l * D_MODEL * D_MODEL,
        fc1_w + (size_t)l * D_MODEL * D_FF,  fc2_w + (size_t)l * D_FF * D_MODEL,
        qkvT, outT, f1T, f2T);
    ln_kernel<<<NTOK, 256, 0, stream>>>(resid_in, ln1_w + l * D_MODEL, ln1_b + l * D_MODEL, h_b);
    gemm_kernel<0, 128><<<dim3(QKV_N / 128, NTOK / 128), 256, 0, stream>>>(
        h_b, qkvT, qkv_b + l * QKV_N, nullptr, nullptr, qkv_a, NTOK, QKV_N, D_MODEL);
    attn_kernel<<<dim3(SEQ / 64, 2 * NHEAD), 256, 0, stream>>>(qkv_a, at_b);
    gemm_kernel<2, 64><<<dim3(D_MODEL / 64, NTOK / 128), 256, 0, stream>>>(
        at_b, outT, out_b + l * D_MODEL, resid_in, buf_x2, nullptr, NTOK, D_MODEL, D_MODEL);
    ln_kernel<<<NTOK, 256, 0, stream>>>(buf_x2, ln2_w + l * D_MODEL, ln2_b + l * D_MODEL, h_b);
    gemm_kernel<1, 128><<<dim3(D_FF / 128, NTOK / 128), 256, 0, stream>>>(
        h_b, f1T, fc1_b + l * D_FF, nullptr, nullptr, mlp_b, NTOK, D_FF, D_MODEL);
    float* x_next = (l < 3) ? buf_x : (float*)d_out;
    gemm_kernel<2, 64><<<dim3(D_MODEL / 64, NTOK / 128), 256, 0, stream>>>(
        mlp_b, f2T, fc2_b + l * D_MODEL, buf_x2, x_next, nullptr, NTOK, D_MODEL, D_FF);
  }
  (void)in_sizes; (void)n_in; (void)out_size; (void)ws_size;
}